// Round 1
// baseline (625.572 us; speedup 1.0000x reference)
//
#include <hip/hip_runtime.h>
#include <hip/hip_bf16.h>
#include <math.h>

#define D_MODEL 1024
#define NHEADS  16
#define HDIM    64
#define BATCH   4
#define SEQ     2048

typedef __attribute__((ext_vector_type(8))) short bf16x8;
typedef __attribute__((ext_vector_type(4))) float f32x4;

__device__ __forceinline__ unsigned short f2bf(float f) {
  union { float f; unsigned u; } v; v.f = f;
  unsigned r = v.u + 0x7FFFu + ((v.u >> 16) & 1u);   // RNE
  return (unsigned short)(r >> 16);
}

// C[M x N] = A[M x 1024] @ W[1024 x N] + bias
// MODE 0: A fp32 (=x), N=3072, scatter Q(,*0.125)/K/V bf16 to (B,H,T,HD)
// MODE 1: A bf16 (=y), N=1024, write fp32 Out
template<int MODE>
__global__ __launch_bounds__(256) void gemm_kernel(
    const void* __restrict__ Ap, const float* __restrict__ W,
    const float* __restrict__ bias,
    unsigned short* __restrict__ Qb, unsigned short* __restrict__ Kb,
    unsigned short* __restrict__ Vb,
    float* __restrict__ Out, int N)
{
  const int bn = blockIdx.x * 64;
  const int bm = blockIdx.y * 64;
  const int tid  = threadIdx.x;
  const int lane = tid & 63;
  const int wave = tid >> 6;
  const int quad = lane >> 4;
  const int l16  = lane & 15;
  const int wr = wave >> 1, wc = wave & 1;

  __shared__ __align__(16) unsigned short As[64][72];  // [m][k], pad->144B rows
  __shared__ __align__(16) unsigned short Bt[64][72];  // transposed: [n][k]

  f32x4 acc[2][2] = {};

  const int ar  = tid >> 2;          // 0..63
  const int ac0 = (tid & 3) * 16;    // 0,16,32,48

  for (int k0 = 0; k0 < D_MODEL; k0 += 64) {
    // ---- stage A tile (cast fp32->bf16 if MODE 0) ----
    if (MODE == 0) {
      const float* a = (const float*)Ap + (size_t)(bm + ar) * D_MODEL + k0 + ac0;
      alignas(16) unsigned short tmp[16];
      #pragma unroll
      for (int i = 0; i < 16; i += 4) {
        float4 f = *(const float4*)(a + i);
        tmp[i+0] = f2bf(f.x); tmp[i+1] = f2bf(f.y);
        tmp[i+2] = f2bf(f.z); tmp[i+3] = f2bf(f.w);
      }
      *(uint4*)&As[ar][ac0]     = ((const uint4*)tmp)[0];
      *(uint4*)&As[ar][ac0 + 8] = ((const uint4*)tmp)[1];
    } else {
      const unsigned short* a = (const unsigned short*)Ap + (size_t)(bm + ar) * D_MODEL + k0 + ac0;
      *(uint4*)&As[ar][ac0]     = ((const uint4*)a)[0];
      *(uint4*)&As[ar][ac0 + 8] = ((const uint4*)a)[1];
    }
    // ---- stage B tile transposed (fp32 W -> bf16 Bt[n][k]) ----
    {
      const float* w = W + (size_t)(k0 + ar) * N + bn + ac0;
      #pragma unroll
      for (int i = 0; i < 16; i += 4) {
        float4 f = *(const float4*)(w + i);
        Bt[ac0+i+0][ar] = f2bf(f.x);
        Bt[ac0+i+1][ar] = f2bf(f.y);
        Bt[ac0+i+2][ar] = f2bf(f.z);
        Bt[ac0+i+3][ar] = f2bf(f.w);
      }
    }
    __syncthreads();

    #pragma unroll
    for (int kk = 0; kk < 2; kk++) {
      bf16x8 af[2], bfv[2];
      #pragma unroll
      for (int mi = 0; mi < 2; mi++)
        af[mi] = *(const bf16x8*)&As[wr*32 + mi*16 + l16][kk*32 + quad*8];
      #pragma unroll
      for (int ni = 0; ni < 2; ni++)
        bfv[ni] = *(const bf16x8*)&Bt[wc*32 + ni*16 + l16][kk*32 + quad*8];
      #pragma unroll
      for (int mi = 0; mi < 2; mi++)
        #pragma unroll
        for (int ni = 0; ni < 2; ni++)
          acc[mi][ni] = __builtin_amdgcn_mfma_f32_16x16x32_bf16(af[mi], bfv[ni], acc[mi][ni], 0, 0, 0);
    }
    __syncthreads();
  }

  // ---- epilogue ----
  #pragma unroll
  for (int mi = 0; mi < 2; mi++) {
    #pragma unroll
    for (int ni = 0; ni < 2; ni++) {
      const int n = bn + wc*32 + ni*16 + l16;
      const float bv = bias[n];
      #pragma unroll
      for (int r = 0; r < 4; r++) {
        const int m = bm + wr*32 + mi*16 + quad*4 + r;   // C/D: row=quad*4+reg, col=l16
        float val = acc[mi][ni][r] + bv;
        if (MODE == 0) {
          const int which = n >> 10;
          const int c = n & 1023;
          const int h = c >> 6, hd = c & 63;
          const int b = m >> 11, t = m & 2047;
          const size_t idx = ((size_t)((b*NHEADS + h)*SEQ + t)) * HDIM + hd;
          if (which == 0)      Qb[idx] = f2bf(val * 0.125f);   // fold 1/sqrt(64)
          else if (which == 1) Kb[idx] = f2bf(val);
          else                 Vb[idx] = f2bf(val);
        } else {
          Out[(size_t)m * N + n] = val;
        }
      }
    }
  }
}

// Flash attention: 1 block = one (b,h), 64 queries; wave w owns queries [qb0+16w, +16)
__global__ __launch_bounds__(256) void attn_kernel(
    const unsigned short* __restrict__ Qb,
    const unsigned short* __restrict__ Kb,
    const unsigned short* __restrict__ Vb,
    unsigned short* __restrict__ Yb)
{
  const int qb0  = blockIdx.x * 64;
  const int bh   = blockIdx.y;
  const int tid  = threadIdx.x;
  const int wave = tid >> 6;
  const int lane = tid & 63;
  const int quad = lane >> 4;
  const int l16  = lane & 15;

  __shared__ __align__(16) unsigned short VT[64][72];     // [hd][key] (transposed V tile)
  __shared__ __align__(16) unsigned short Pl[4][16][72];  // per-wave P: [qrow][key]

  const size_t base = (size_t)bh * SEQ * HDIM;
  const int qrow0 = qb0 + wave * 16;

  // Q A-frags (scale pre-folded): lane holds Q[qrow0+l16][kk*32+quad*8 ..+7]
  bf16x8 qf[2];
  #pragma unroll
  for (int kk = 0; kk < 2; kk++)
    qf[kk] = *(const bf16x8*)(Qb + base + (size_t)(qrow0 + l16) * HDIM + kk*32 + quad*8);

  f32x4 acc[4] = {};           // O: col hd = nf*16+l16, row q = quad*4+r
  float mrow[4], lrow[4];
  #pragma unroll
  for (int r = 0; r < 4; r++) { mrow[r] = -INFINITY; lrow[r] = 0.f; }

  const int skey = tid >> 2;          // staging: key row 0..63
  const int sh0  = (tid & 3) * 16;    // hd chunk

  const int ntiles = (qb0 >> 6) + 1;  // causal: tiles 0..qb0/64
  for (int it = 0; it < ntiles; it++) {
    const int kb = it * 64;

    // ---- stage V^T into LDS ----
    {
      const unsigned short* v = Vb + base + (size_t)(kb + skey) * HDIM + sh0;
      alignas(16) unsigned short tmp[16];
      ((uint4*)tmp)[0] = ((const uint4*)v)[0];
      ((uint4*)tmp)[1] = ((const uint4*)v)[1];
      #pragma unroll
      for (int i = 0; i < 16; i++) VT[sh0 + i][skey] = tmp[i];
    }
    __syncthreads();

    // ---- S = Q K^T (B-frags straight from global: K[key][hd] hd-contiguous) ----
    f32x4 s[4] = {};
    #pragma unroll
    for (int kk = 0; kk < 2; kk++) {
      #pragma unroll
      for (int nf = 0; nf < 4; nf++) {
        bf16x8 kf = *(const bf16x8*)(Kb + base + (size_t)(kb + nf*16 + l16) * HDIM + kk*32 + quad*8);
        s[nf] = __builtin_amdgcn_mfma_f32_16x16x32_bf16(qf[kk], kf, s[nf], 0, 0, 0);
      }
    }

    // ---- causal mask + row max ----
    float tmax[4];
    #pragma unroll
    for (int r = 0; r < 4; r++) tmax[r] = -INFINITY;
    #pragma unroll
    for (int nf = 0; nf < 4; nf++) {
      const int kcol = kb + nf*16 + l16;
      #pragma unroll
      for (int r = 0; r < 4; r++) {
        const int q = qrow0 + quad*4 + r;
        float sv = s[nf][r];
        sv = (kcol > q) ? -INFINITY : sv;
        s[nf][r] = sv;
        tmax[r] = fmaxf(tmax[r], sv);
      }
    }
    #pragma unroll
    for (int off = 1; off < 16; off <<= 1)
      #pragma unroll
      for (int r = 0; r < 4; r++)
        tmax[r] = fmaxf(tmax[r], __shfl_xor(tmax[r], off, 64));

    float alpha[4], tsum[4];
    #pragma unroll
    for (int r = 0; r < 4; r++) {
      const float mn = fmaxf(mrow[r], tmax[r]);   // finite: tile 0 always has valid keys
      alpha[r] = __expf(mrow[r] - mn);
      mrow[r] = mn;
      tsum[r] = 0.f;
    }

    // ---- P = exp(S - m), write to per-wave LDS (C-layout -> A-layout round trip) ----
    #pragma unroll
    for (int nf = 0; nf < 4; nf++) {
      #pragma unroll
      for (int r = 0; r < 4; r++) {
        const float p = __expf(s[nf][r] - mrow[r]);
        tsum[r] += p;
        Pl[wave][quad*4 + r][nf*16 + l16] = f2bf(p);
      }
    }
    #pragma unroll
    for (int off = 1; off < 16; off <<= 1)
      #pragma unroll
      for (int r = 0; r < 4; r++)
        tsum[r] += __shfl_xor(tsum[r], off, 64);

    #pragma unroll
    for (int r = 0; r < 4; r++) lrow[r] = lrow[r] * alpha[r] + tsum[r];
    #pragma unroll
    for (int nf = 0; nf < 4; nf++)
      #pragma unroll
      for (int r = 0; r < 4; r++)
        acc[nf][r] *= alpha[r];

    __syncthreads();   // P LDS ordering (conservative) + all waves have VT staged

    // ---- O += P V ----
    #pragma unroll
    for (int kk = 0; kk < 2; kk++) {
      bf16x8 pf = *(const bf16x8*)&Pl[wave][l16][kk*32 + quad*8];
      #pragma unroll
      for (int nf = 0; nf < 4; nf++) {
        bf16x8 vf = *(const bf16x8*)&VT[nf*16 + l16][kk*32 + quad*8];
        acc[nf] = __builtin_amdgcn_mfma_f32_16x16x32_bf16(pf, vf, acc[nf], 0, 0, 0);
      }
    }
    __syncthreads();   // protect VT before next-iter staging
  }

  // ---- O /= l, write y (B,T,C) bf16 ----
  const int h = bh & (NHEADS - 1);
  const int b = bh >> 4;
  #pragma unroll
  for (int r = 0; r < 4; r++) {
    const float inv = 1.0f / lrow[r];
    const int t = qrow0 + quad*4 + r;
    const size_t off = ((size_t)(b * SEQ + t)) * D_MODEL + h * HDIM;
    #pragma unroll
    for (int nf = 0; nf < 4; nf++)
      Yb[off + nf*16 + l16] = f2bf(acc[nf][r] * inv);
  }
}

extern "C" void kernel_launch(void* const* d_in, const int* in_sizes, int n_in,
                              void* d_out, int out_size, void* d_ws, size_t ws_size,
                              hipStream_t stream) {
  const float* x     = (const float*)d_in[0];
  const float* w_qkv = (const float*)d_in[1];
  const float* b_qkv = (const float*)d_in[2];
  const float* w_out = (const float*)d_in[3];
  const float* b_out = (const float*)d_in[4];
  float* out = (float*)d_out;

  const size_t SZ = (size_t)BATCH * NHEADS * SEQ * HDIM;  // 8,388,608 elems
  unsigned short* Qb = (unsigned short*)d_ws;             // bf16, 16 MiB each
  unsigned short* Kb = Qb + SZ;
  unsigned short* Vb = Kb + SZ;
  unsigned short* Yb = Vb + SZ;                            // total 64 MiB of ws

  // QKV projection + bias + scatter to (B,H,T,HD), q pre-scaled by 1/8
  gemm_kernel<0><<<dim3(3*D_MODEL/64, BATCH*SEQ/64), 256, 0, stream>>>(
      x, w_qkv, b_qkv, Qb, Kb, Vb, nullptr, 3*D_MODEL);
  // causal flash attention -> y (B,T,C) bf16
  attn_kernel<<<dim3(SEQ/64, BATCH*NHEADS), 256, 0, stream>>>(Qb, Kb, Vb, Yb);
  // output projection + bias -> fp32 out
  gemm_kernel<1><<<dim3(D_MODEL/64, BATCH*SEQ/64), 256, 0, stream>>>(
      Yb, w_out, b_out, nullptr, nullptr, nullptr, out, D_MODEL);
}